// Round 11
// baseline (4126.791 us; speedup 1.0000x reference)
//
#include <hip/hip_runtime.h>
#include <stdint.h>
#include <math.h>

// ============================================================================
// RBM contrastive divergence (K_GIBBS=1), B=64 sequential steps.
// Low-rank restructure: W_t = W0 + LR * sum_{s<t} (v0_s hinit_s^T - v_s hbin_s^T)
//  h_t  = sig(b_t + C[t] + LR*sum_s(hinit_s*G0[s][t] - hbin_s*GV[s][t]))
//  v_t  = sig(a_t + W0 h_t + LR*sum_s(v0_s*(hinit_s.h_t) - v_s*(hbin_s.h_t)))
// C = V0 @ W0 (one GEMM), G0 = V0 V0^T, GV[s][t] = v_s . v0_t.
// GV is now produced incrementally: gemv(t) writes per-block partials
// (Gpart), hbc(t+1) reduces them (fixed topology -> deterministic). k_gv gone.
// ws_size >= 21186560 proven by round-1 (NCH=16 Cpart at 4.4MB+16MB passed).
// ============================================================================

#define NB   64
#define FLAT 12288
#define HID  4096
#define LRf  0.01f
#define LRd  0.01
#define RNG_MODE 0
#define GEMV_BLOCKS (FLAT / 8)   // 1536

// ---- workspace layout (byte offsets) ----
#define OFF_KEYS   0u          // 64*4 u32
#define OFF_B      1024u       // 4096 f32
#define OFF_A      17408u      // 12288 f32
#define OFF_H      66560u      // 4096 f32
#define OFF_ALP    82944u      // 16*64 f64 block-partial alpha
#define OFF_BEP    91136u      // 16*64 f64 block-partial beta
#define OFF_G0     99328u      // 64*64 f64
#define OFF_GV     132096u     // 64*64 f64
#define OFF_HIB    164864u     // 64*128 u32 hinit bitmasks (row-major)
#define OFF_HBB    197632u     // 64*128 u32 hbin bitmasks (row-major)
#define OFF_C      230400u     // 64*4096 f32
#define OFF_VT     4424704u    // 12288*64 f32 (transposed v_s, gemv correction)
#define OFF_V0T    7570432u    // 12288*64 f32 (transposed v0)
#define OFF_HIBC   10716160u   // 4096 u64 transposed hinit columns (bit s)
#define OFF_HBBC   10748928u   // 4096 u64 transposed hbin columns
#define OFF_CPART  10781696u   // NCH*64*4096 f32 — disjoint from everything
#define NCH 8                  // Cpart 8MB: ends 19170304 <= ws (>=21186560)
#define OFF_GPART  19170304u   // 1536*64 f64 = 786432 -> ends 19956736

// ---------------------------------------------------------------------------
__device__ __forceinline__ void tf(uint32_t k0, uint32_t k1,
                                   uint32_t x0, uint32_t x1,
                                   uint32_t& o0, uint32_t& o1) {
  uint32_t ks[3] = {k0, k1, k0 ^ k1 ^ 0x1BD11BDAu};
  x0 += ks[0]; x1 += ks[1];
  const int R0[4] = {13, 15, 26, 6};
  const int R1[4] = {17, 29, 16, 24};
#pragma unroll
  for (int i = 0; i < 5; ++i) {
    const int* r = (i & 1) ? R1 : R0;
#pragma unroll
    for (int q = 0; q < 4; ++q) {
      x0 += x1;
      x1 = (x1 << r[q]) | (x1 >> (32 - r[q]));
      x1 ^= x0;
    }
    x0 += ks[(i + 1) % 3];
    x1 += ks[(i + 2) % 3] + (uint32_t)(i + 1);
  }
  o0 = x0; o1 = x1;
}

__device__ __forceinline__ float u01(uint32_t bits) {
  uint32_t fb = (bits >> 9) | 0x3f800000u;
  return __uint_as_float(fb) - 1.0f;
}

// ---------------------------------------------------------------------------
__global__ void k_setup(const float* a_in, const float* b_in,
                        float* a_cur, float* b_cur, uint32_t* keys4) {
  int gid = blockIdx.x * blockDim.x + threadIdx.x;
  int stride = gridDim.x * blockDim.x;
  for (int i = gid; i < FLAT; i += stride) a_cur[i] = a_in[i];
  for (int i = gid; i < HID; i += stride) b_cur[i] = b_in[i];
  if (gid < NB) {
    uint32_t t = (uint32_t)gid;
    uint32_t kt0, kt1, o0, o1, p0, p1;
#if RNG_MODE == 0
    tf(0u, 42u, 0u, t, kt0, kt1);
    tf(kt0, kt1, 0u, 0u, o0, o1);
    tf(kt0, kt1, 0u, 1u, p0, p1);
    keys4[4 * gid + 0] = o0; keys4[4 * gid + 1] = o1;
    keys4[4 * gid + 2] = p0; keys4[4 * gid + 3] = p1;
#else
    if (t < 32) {
      tf(0u, 42u, 2 * t,     64 + 2 * t, o0, o1); kt0 = o0;
      tf(0u, 42u, 2 * t + 1, 65 + 2 * t, o0, o1); kt1 = o0;
    } else {
      tf(0u, 42u, 2 * t - 64, 2 * t,     o0, o1); kt0 = o1;
      tf(0u, 42u, 2 * t - 63, 2 * t + 1, o0, o1); kt1 = o1;
    }
    uint32_t a0, a1, b0, b1;
    tf(kt0, kt1, 0u, 2u, a0, a1);
    tf(kt0, kt1, 1u, 3u, b0, b1);
    keys4[4 * gid + 0] = a0; keys4[4 * gid + 1] = b0;
    keys4[4 * gid + 2] = a1; keys4[4 * gid + 3] = b1;
#endif
  }
}

// v0T[i][s] = v0[s][i]
__global__ void k_vt(const float* v0all, float* v0T) {
  int i = blockIdx.x * 256 + threadIdx.x;
#pragma unroll 8
  for (int s = 0; s < NB; ++s)
    v0T[(size_t)i * NB + s] = v0all[(size_t)s * FLAT + i];
}

// ---------------------------------------------------------------------------
// G0: block per (s,t) pair (4096 blocks).
// ---------------------------------------------------------------------------
__global__ __launch_bounds__(256) void k_g0(const float* v0all, double* G0) {
  const int t = blockIdx.x, s = blockIdx.y;
  const float4* vs = (const float4*)(v0all + (size_t)s * FLAT);
  const float4* vt = (const float4*)(v0all + (size_t)t * FLAT);
  double acc = 0.0;
  for (int e = threadIdx.x; e < FLAT / 4; e += 256) {
    float4 a = vs[e], b = vt[e];
    acc += (double)a.x * b.x + (double)a.y * b.y +
           (double)a.z * b.z + (double)a.w * b.w;
  }
  for (int m = 32; m; m >>= 1) acc += __shfl_xor(acc, m, 64);
  __shared__ double red[4];
  int wv = threadIdx.x >> 6, lane = threadIdx.x & 63;
  if (lane == 0) red[wv] = acc;
  __syncthreads();
  if (threadIdx.x == 0) G0[s * NB + t] = red[0] + red[1] + red[2] + red[3];
}

// ---------------------------------------------------------------------------
// C partial GEMM v4: two-tile LDS GEMM, un-capped grid.
//  v3 was grid-limited: 384 blocks = 1.5/CU, occ 15%, VALUBusy 28%.
//  Now 32-lane j split + NCH=8 (Cpart moved to free ws space, no aliasing):
//  grid 128x8 = 1024 blocks = 4/CU co-resident.
// 256 thr = 32 j-lanes x 8 t-groups, acc[8] each.
// ---------------------------------------------------------------------------
__global__ __launch_bounds__(256) void k_cgemm(const float* v0T, const float* W0,
                                               float* Cpart) {
  const int jl = threadIdx.x & 31;
  const int tth = threadIdx.x >> 5;            // 0..7
  const int j0 = blockIdx.x * 32;
  const int ilen = FLAT / NCH;                 // 1536, /64 = 24 tiles
  const int ibeg = blockIdx.y * ilen, iend = ibeg + ilen;
  __shared__ float lv[64 * 68];                // v tile [ii][t], pad 68
  __shared__ float lw[64 * 36];                // W tile [ii][j], pad 36
  float acc[8];
#pragma unroll
  for (int k = 0; k < 8; ++k) acc[k] = 0.f;
  for (int i0 = ibeg; i0 < iend; i0 += 64) {
    __syncthreads();
    // stage v tile: v0T rows are 64 floats -> linear float4, coalesced
    const float4* vsrc = (const float4*)(v0T + (size_t)i0 * NB);
#pragma unroll
    for (int k = 0; k < 4; ++k) {
      int f = threadIdx.x + k * 256;
      int row = f >> 4, c4 = f & 15;
      *(float4*)(&lv[row * 68 + c4 * 4]) = vsrc[f];
    }
    // stage W tile: 128B contiguous per 8-lane group, coalesced
#pragma unroll
    for (int k = 0; k < 2; ++k) {
      int f = threadIdx.x + k * 256;
      int row = f >> 3, c4 = f & 7;
      *(float4*)(&lw[row * 36 + c4 * 4]) =
          *(const float4*)(W0 + (size_t)(i0 + row) * HID + j0 + c4 * 4);
    }
    __syncthreads();
#pragma unroll 2
    for (int ii = 0; ii < 64; ++ii) {
      float w = lw[ii * 36 + jl];
      const float* lp = &lv[ii * 68 + tth * 8];
      float4 h0 = *(const float4*)(lp);
      float4 h1 = *(const float4*)(lp + 4);
      acc[0] += w * h0.x; acc[1] += w * h0.y;
      acc[2] += w * h0.z; acc[3] += w * h0.w;
      acc[4] += w * h1.x; acc[5] += w * h1.y;
      acc[6] += w * h1.z; acc[7] += w * h1.w;
    }
  }
#pragma unroll
  for (int k = 0; k < 8; ++k)
    Cpart[((size_t)blockIdx.y * NB + tth * 8 + k) * HID + j0 + jl] = acc[k];
}

__global__ void k_creduce(const float* Cpart, float* C) {
  int gid = blockIdx.x * blockDim.x + threadIdx.x;
  if (gid >= NB * HID) return;
  double s = 0.0;
  for (int c = 0; c < NCH; ++c) s += (double)Cpart[(size_t)c * NB * HID + gid];
  C[gid] = (float)s;
}

// ---------------------------------------------------------------------------
// Hidden-side, 16 blocks x 256 thr:
//  prelude (t>0): reduce Gpart columns -> GV row t-1. Every block computes
//    column t for its own gvc[t-1] (identical fixed topology -> bitwise same);
//    columns tp>t distributed across blocks (tp = blockIdx + 16c) and written
//    to GV for future steps.
//  phase B: h_t from transposed mask columns (ctz loop).
//  phase C: threefry sample; ballot row-mask; column-bit; b update.
//  phase D: block-partial alpha/beta dots for s<=t.
// ---------------------------------------------------------------------------
__global__ __launch_bounds__(256) void k_hbc(int t, const float* Call,
                                             const double* G0, double* GV,
                                             const double* Gpart,
                                             float* b_cur, float* h_cur,
                                             uint32_t* Hib, uint32_t* Hbb,
                                             uint64_t* HibC, uint64_t* HbbC,
                                             double* alp, double* bep,
                                             const uint32_t* keys4) {
  const int tid = threadIdx.x;
  const int lane = tid & 63, wv = tid >> 6;
  const int j = blockIdx.x * 256 + tid;
  __shared__ double g0c[NB], gvc[NB];
  __shared__ double colred[4];
  __shared__ float h_blk[256];
  __shared__ unsigned char ib_blk[256], bb_blk[256];
  __shared__ uint32_t ldsI[NB][8], ldsB[NB][8];   // this block's mask words, s<t
  for (int s = tid; s < NB; s += 256) { g0c[s] = G0[s * NB + t]; gvc[s] = GV[s * NB + t]; }
  for (int idx = tid; idx < t * 8; idx += 256) {
    int s = idx >> 3, w = idx & 7;
    ldsI[s][w] = Hib[s * 128 + blockIdx.x * 8 + w];
    ldsB[s][w] = Hbb[s * 128 + blockIdx.x * 8 + w];
  }
  // ---- prelude: GV row t-1 from Gpart (written by gemv(t-1)) ----
  if (t > 0) {
#pragma unroll 1
    for (int c = 0; c < 5; ++c) {
      int tp = (c == 4) ? t : ((int)blockIdx.x + 16 * c);
      if (c < 4 && tp <= t) continue;          // block-uniform condition
      double ps = 0.0;
      for (int b = tid; b < GEMV_BLOCKS; b += 256)
        ps += Gpart[(size_t)b * NB + tp];
      for (int m = 32; m; m >>= 1) ps += __shfl_xor(ps, m, 64);
      if (lane == 0) colred[wv] = ps;
      __syncthreads();
      if (tid == 0) {
        double tot = colred[0] + colred[1] + colred[2] + colred[3];
        if (c == 4) gvc[t - 1] = tot;          // own needed scalar
        else GV[(size_t)(t - 1) * NB + tp] = tot;  // for future steps
      }
      __syncthreads();
    }
  }
  __syncthreads();
  // ---- phase B: logit via transposed columns ----
  uint64_t rawI = (t == 0) ? 0ull : HibC[j];
  uint64_t rawB = (t == 0) ? 0ull : HbbC[j];
  const uint64_t mlow = (t == 0) ? 0ull : ((1ull << t) - 1ull);
  uint64_t mi64 = rawI & mlow, mb64 = rawB & mlow;
  double accp = 0.0, accm = 0.0;
  while (mi64) { int s = __builtin_ctzll(mi64); accp += g0c[s]; mi64 &= mi64 - 1; }
  while (mb64) { int s = __builtin_ctzll(mb64); accm += gvc[s]; mb64 &= mb64 - 1; }
  double lg = (double)b_cur[j] + (double)Call[(size_t)t * HID + j] + LRd * (accp - accm);
  float h = (float)(1.0 / (1.0 + exp(-lg)));
  h_cur[j] = h;
  // ---- phase C: sample ----
  uint32_t o0, o1;
  uint32_t kb0 = keys4[4 * t], kb1 = keys4[4 * t + 1];
  uint32_t ki0 = keys4[4 * t + 2], ki1 = keys4[4 * t + 3];
#if RNG_MODE == 0
  tf(kb0, kb1, 0u, (uint32_t)j, o0, o1); float ub = u01(o0 ^ o1);
  tf(ki0, ki1, 0u, (uint32_t)j, o0, o1); float ui = u01(o0 ^ o1);
#else
  uint32_t m = (uint32_t)(j & (HID / 2 - 1));
  tf(kb0, kb1, m, m + HID / 2, o0, o1); float ub = u01(j < HID / 2 ? o0 : o1);
  tf(ki0, ki1, m, m + HID / 2, o0, o1); float ui = u01(j < HID / 2 ? o0 : o1);
#endif
  bool hb = h > ub, hi = h > ui;
  unsigned long long mb = __ballot(hb), mi = __ballot(hi);
  const int word = j >> 5;
  if (lane == 0) {
    Hbb[t * 128 + word]     = (uint32_t)mb;
    Hbb[t * 128 + word + 1] = (uint32_t)(mb >> 32);
    Hib[t * 128 + word]     = (uint32_t)mi;
    Hib[t * 128 + word + 1] = (uint32_t)(mi >> 32);
  }
  HibC[j] = rawI | ((uint64_t)(hi ? 1 : 0) << t);   // thread j owns word j
  HbbC[j] = rawB | ((uint64_t)(hb ? 1 : 0) << t);
  b_cur[j] += LRf * ((hi ? 1.f : 0.f) - (hb ? 1.f : 0.f));
  h_blk[tid] = h; ib_blk[tid] = hi ? 1 : 0; bb_blk[tid] = hb ? 1 : 0;
  __syncthreads();
  // ---- phase D: block-partial dots, s <= t (masks from LDS) ----
  for (int task = wv; task < 2 * (t + 1); task += 4) {
    int s = task >> 1;
    const bool useB = task & 1;
    double p = 0.0;
#pragma unroll
    for (int q = 0; q < 4; ++q) {
      int jj = q * 64 + lane;
      bool on;
      if (s == t) on = (useB ? bb_blk[jj] : ib_blk[jj]) != 0;
      else {
        uint32_t w32 = useB ? ldsB[s][jj >> 5] : ldsI[s][jj >> 5];
        on = (w32 >> (jj & 31)) & 1u;
      }
      if (on) p += (double)h_blk[jj];
    }
    for (int m2 = 32; m2; m2 >>= 1) p += __shfl_xor(p, m2, 64);
    if (lane == 0) {
      if (useB) bep[(size_t)blockIdx.x * NB + s] = p;
      else      alp[(size_t)blockIdx.x * NB + s] = p;
    }
  }
}

// ---------------------------------------------------------------------------
// Big GEMV: 512 thr, 8 rows/block (wave per row), grid FLAT/8 = 1536.
// Epilogue (t<NB-1) emits Gpart[block][tp] = sum_rows v[row]*v0T[row][tp]
// (fixed tree -> deterministic) — replaces the k_gv kernel entirely.
// t==NB: final mode, write d_out.
// ---------------------------------------------------------------------------
__global__ __launch_bounds__(512) void k_gemv(int t, const float* W0,
                                              const float* v0T, const float* h_cur,
                                              const double* alp, const double* bep,
                                              float* a_cur, float* Vt,
                                              double* Gpart, float* out) {
  __shared__ float hs[HID];
  __shared__ double als[NB], bes[NB];
  __shared__ double gp[8][NB];
  const int tid = threadIdx.x;
  for (int e = tid; e < HID / 4; e += 512)
    ((float4*)hs)[e] = ((const float4*)h_cur)[e];
  if (tid < NB) {
    double asum = 0.0, bsum = 0.0;
#pragma unroll
    for (int b = 0; b < 16; ++b) {
      asum += alp[(size_t)b * NB + tid];
      bsum += bep[(size_t)b * NB + tid];
    }
    als[tid] = asum; bes[tid] = bsum;
  }
  __syncthreads();
  const int wv = tid >> 6, lane = tid & 63;
  const int row = blockIdx.x * 8 + wv;
  const float4* wr = (const float4*)(W0 + (size_t)row * HID);
  double acc = 0.0;
#pragma unroll
  for (int c = 0; c < 16; ++c) {
    float4 w = wr[c * 64 + lane];
    float4 hh = ((const float4*)hs)[c * 64 + lane];
    acc += (double)w.x * hh.x + (double)w.y * hh.y +
           (double)w.z * hh.z + (double)w.w * hh.w;
  }
  const int smax = (t > NB - 1) ? NB : t;
  double v0l = (double)v0T[(size_t)row * NB + lane];   // also feeds Gpart
  if (lane < smax) {
    acc += LRd * (v0l * als[lane]
                  - (double)Vt[(size_t)row * NB + lane] * bes[lane]);
  }
  for (int m = 32; m; m >>= 1) acc += __shfl_xor(acc, m, 64);
  // all lanes hold the full sum after the butterfly
  double lg = (double)a_cur[row] + acc;
  float vv = (float)(1.0 / (1.0 + exp(-lg)));
  if (t == NB) {
    if (lane == 0) out[row] = vv;
  } else {
    if (lane == 0) {
      Vt[(size_t)row * NB + t] = vv;
      a_cur[row] += LRf * (v0T[(size_t)row * NB + t] - vv);
    }
    if (t < NB - 1) gp[wv][lane] = (double)vv * v0l;
  }
  __syncthreads();
  if (t < NB - 1 && tid < NB) {
    double s = 0.0;
#pragma unroll
    for (int w = 0; w < 8; ++w) s += gp[w][tid];
    Gpart[(size_t)blockIdx.x * NB + tid] = s;
  }
}

// ---------------------------------------------------------------------------
extern "C" void kernel_launch(void* const* d_in, const int* in_sizes, int n_in,
                              void* d_out, int out_size, void* d_ws, size_t ws_size,
                              hipStream_t stream) {
  const float* inputs = (const float*)d_in[0];
  const float* W0     = (const float*)d_in[1];
  const float* a_in   = (const float*)d_in[2];
  const float* b_in   = (const float*)d_in[3];
  float* out = (float*)d_out;

  char* ws = (char*)d_ws;
  uint32_t* keys4 = (uint32_t*)(ws + OFF_KEYS);
  float* b_cur = (float*)(ws + OFF_B);
  float* a_cur = (float*)(ws + OFF_A);
  float* h_cur = (float*)(ws + OFF_H);
  double* alp  = (double*)(ws + OFF_ALP);
  double* bep  = (double*)(ws + OFF_BEP);
  double* G0   = (double*)(ws + OFF_G0);
  double* GV   = (double*)(ws + OFF_GV);
  uint32_t* Hib = (uint32_t*)(ws + OFF_HIB);
  uint32_t* Hbb = (uint32_t*)(ws + OFF_HBB);
  uint64_t* HibC = (uint64_t*)(ws + OFF_HIBC);
  uint64_t* HbbC = (uint64_t*)(ws + OFF_HBBC);
  float* C     = (float*)(ws + OFF_C);
  float* Vt    = (float*)(ws + OFF_VT);
  float* v0T   = (float*)(ws + OFF_V0T);
  float* Cpart = (float*)(ws + OFF_CPART);
  double* Gpart = (double*)(ws + OFF_GPART);

  hipLaunchKernelGGL(k_setup, dim3(48), dim3(256), 0, stream,
                     a_in, b_in, a_cur, b_cur, keys4);
  hipLaunchKernelGGL(k_g0, dim3(NB, NB), dim3(256), 0, stream, inputs, G0);
  hipLaunchKernelGGL(k_vt, dim3(FLAT / 256), dim3(256), 0, stream, inputs, v0T);
  hipLaunchKernelGGL(k_cgemm, dim3(HID / 32, NCH), dim3(256), 0, stream,
                     v0T, W0, Cpart);
  hipLaunchKernelGGL(k_creduce, dim3((NB * HID + 255) / 256), dim3(256), 0,
                     stream, Cpart, C);

  for (int t = 0; t < NB; ++t) {
    hipLaunchKernelGGL(k_hbc, dim3(HID / 256), dim3(256), 0, stream,
                       t, C, G0, GV, Gpart, b_cur, h_cur, Hib, Hbb, HibC, HbbC,
                       alp, bep, keys4);
    hipLaunchKernelGGL(k_gemv, dim3(GEMV_BLOCKS), dim3(512), 0, stream,
                       t, W0, v0T, h_cur, alp, bep, a_cur, Vt, Gpart, out);
  }
  // final: v = sig(a_64 + W_64 h_63); alpha/beta for s<=63 already from k_hbc(63)
  hipLaunchKernelGGL(k_gemv, dim3(GEMV_BLOCKS), dim3(512), 0, stream,
                     NB, W0, v0T, h_cur, alp, bep, a_cur, Vt, Gpart, out);
}